// Round 1
// baseline (956.976 us; speedup 1.0000x reference)
//
#include <hip/hip_runtime.h>
#include <hip/hip_bf16.h>
#include <math.h>

// ---------------- problem constants ----------------
#define BATCH 2
#define SEQ   256
#define DMODL 768
#define DIEXP 1536   // DI
#define NHEAD 24
#define HDIM  64
#define NSTATE 64
#define RRANK 2
#define NANG  16
#define HALFSPLIT 32
#define DINP  3416
#define AFLOOR 1e-4f
#define EPSV   1e-5f

// column offsets inside proj row (length DINP)
#define COL_Z    0
#define COL_X    1536
#define COL_B    3072
#define COL_C    3200
#define COL_DT   3328
#define COL_A    3352
#define COL_TRAP 3376
#define COL_ANG  3400

__device__ __forceinline__ float softplusf(float x) {
    if (x > 20.f) return x;
    return log1pf(expf(x));
}
__device__ __forceinline__ float sigmoidf_(float x) {
    return 1.f / (1.f + expf(-x));
}

// ---------------- generic fp32 GEMM: C[M,N] = A[M,K] @ B[N,K]^T ----------------
// BM=BN=64, BK=16, 256 threads, each thread 4x4. K must be divisible by 16.
__global__ __launch_bounds__(256) void gemm_abt(const float* __restrict__ A,
                                                const float* __restrict__ B,
                                                float* __restrict__ C,
                                                int M, int N, int K) {
    __shared__ float As[16][65];
    __shared__ float Bs[16][65];
    const int bm = blockIdx.y * 64, bn = blockIdx.x * 64;
    const int tid = threadIdx.x;
    const int tr = tid / 16, tc = tid % 16;
    float acc[4][4] = {};
    for (int k0 = 0; k0 < K; k0 += 16) {
        for (int i = tid; i < 64 * 16; i += 256) {
            int r = i / 16, c = i % 16;
            float va = 0.f, vb = 0.f;
            if (bm + r < M) va = A[(size_t)(bm + r) * K + k0 + c];
            if (bn + r < N) vb = B[(size_t)(bn + r) * K + k0 + c];
            As[c][r] = va;
            Bs[c][r] = vb;
        }
        __syncthreads();
        #pragma unroll
        for (int kk = 0; kk < 16; ++kk) {
            float a[4], b[4];
            #pragma unroll
            for (int i = 0; i < 4; ++i) a[i] = As[kk][tr * 4 + i];
            #pragma unroll
            for (int j = 0; j < 4; ++j) b[j] = Bs[kk][tc * 4 + j];
            #pragma unroll
            for (int i = 0; i < 4; ++i)
                #pragma unroll
                for (int j = 0; j < 4; ++j) acc[i][j] += a[i] * b[j];
        }
        __syncthreads();
    }
    #pragma unroll
    for (int i = 0; i < 4; ++i) {
        int row = bm + tr * 4 + i;
        if (row >= M) continue;
        #pragma unroll
        for (int j = 0; j < 4; ++j) {
            int col = bn + tc * 4 + j;
            if (col < N) C[(size_t)row * N + col] = acc[i][j];
        }
    }
}

// ---------------- prep1: per (b,l,h) scalars ----------------
__global__ void prep1(const float* __restrict__ proj, const float* __restrict__ dt_bias,
                      float* __restrict__ DTv, float* __restrict__ lamv,
                      float* __restrict__ lav) {
    int idx = blockIdx.x * 256 + threadIdx.x;  // over BATCH*SEQ*NHEAD
    if (idx >= BATCH * SEQ * NHEAD) return;
    int h = idx % NHEAD;
    int l = (idx / NHEAD) % SEQ;
    int b = idx / (NHEAD * SEQ);
    const float* row = proj + (size_t)(b * SEQ + l) * DINP;
    float DT  = softplusf(row[COL_DT + h] + dt_bias[h]);
    float Asp = fmaxf(softplusf(row[COL_A + h]), AFLOOR);
    float la  = -Asp * DT;                 // log(a_t)
    float lam = sigmoidf_(row[COL_TRAP + h]);
    int o = (b * NHEAD + h) * SEQ + l;
    DTv[o] = DT; lamv[o] = lam; lav[o] = la;
}

// ---------------- prep2a: P = inclusive cumsum of log-decay, per (b,h) ----------------
__global__ void prep2a(const float* __restrict__ lav, float* __restrict__ P) {
    int bh = threadIdx.x;
    if (bh >= BATCH * NHEAD) return;
    const float* src = lav + bh * SEQ;
    float* dst = P + bh * SEQ;
    float run = 0.f;
    for (int l = 0; l < SEQ; ++l) { run += src[l]; dst[l] = run; }
}

// ---------------- prep2b: theta = cumsum_l DT*ang, per (b,h,i) ----------------
__global__ void prep2b(const float* __restrict__ proj, const float* __restrict__ DTv,
                       float* __restrict__ theta) {
    int idx = blockIdx.x * 256 + threadIdx.x;  // over BATCH*NHEAD*NANG
    if (idx >= BATCH * NHEAD * NANG) return;
    int i = idx % NANG;
    int h = (idx / NANG) % NHEAD;
    int b = idx / (NANG * NHEAD);
    float run = 0.f;
    for (int l = 0; l < SEQ; ++l) {
        float dt  = DTv[(b * NHEAD + h) * SEQ + l];
        float ang = proj[(size_t)(b * SEQ + l) * DINP + COL_ANG + i];
        run += dt * ang;
        theta[((size_t)(b * SEQ + l) * NHEAD + h) * NANG + i] = run;
    }
}

// ---------------- prep3: RMS-norm + bias + RoPE -> Bh, Ch [(b,r,h),l,n] ----------------
__global__ __launch_bounds__(256) void prep3(const float* __restrict__ proj,
        const float* __restrict__ Bbias, const float* __restrict__ Cbias,
        const float* __restrict__ Bnw, const float* __restrict__ Cnw,
        const float* __restrict__ theta,
        float* __restrict__ Bh, float* __restrict__ Ch) {
    int bl = blockIdx.x;            // over BATCH*SEQ
    int b = bl / SEQ, l = bl % SEQ;
    int tid = threadIdx.x;
    __shared__ float sB[RRANK][NSTATE], sC[RRANK][NSTATE], scale[4];
    __shared__ float thl[NHEAD * NANG];
    const float* row = proj + (size_t)bl * DINP;
    if (tid < 128) {
        int r = tid / 64, n = tid % 64;
        sB[r][n] = row[COL_B + r * NSTATE + n];
    } else {
        int t2 = tid - 128;
        int r = t2 / 64, n = t2 % 64;
        sC[r][n] = row[COL_C + r * NSTATE + n];
    }
    for (int k = tid; k < NHEAD * NANG; k += 256)
        thl[k] = theta[(size_t)bl * NHEAD * NANG + k];
    __syncthreads();
    // RMS reductions: 4 waves, wave g handles (B r0),(B r1),(C r0),(C r1)
    int g = tid / 64, lane = tid % 64;
    float v = (g < 2) ? sB[g][lane] : sC[g - 2][lane];
    float ss = v * v;
    #pragma unroll
    for (int off = 32; off; off >>= 1) ss += __shfl_xor(ss, off);
    if (lane == 0) scale[g] = rsqrtf(ss / NSTATE + EPSV);
    __syncthreads();
    float scB[2] = {scale[0], scale[1]};
    float scC[2] = {scale[2], scale[3]};
    for (int idx = tid; idx < RRANK * NHEAD * NSTATE; idx += 256) {
        int n = idx % NSTATE;
        int h = (idx / NSTATE) % NHEAD;
        int r = idx / (NSTATE * NHEAD);
        float outB, outC;
        if (n < HALFSPLIT) {
            int i = n >> 1;
            int n0 = i * 2, n1 = n0 + 1;
            float th = thl[h * NANG + i];
            float c = cosf(th), s = sinf(th);
            float b0 = sB[r][n0] * scB[r] * Bnw[n0] * Bbias[(h * RRANK + r) * NSTATE + n0];
            float b1 = sB[r][n1] * scB[r] * Bnw[n1] * Bbias[(h * RRANK + r) * NSTATE + n1];
            float c0 = sC[r][n0] * scC[r] * Cnw[n0] * Cbias[(h * RRANK + r) * NSTATE + n0];
            float c1 = sC[r][n1] * scC[r] * Cnw[n1] * Cbias[(h * RRANK + r) * NSTATE + n1];
            outB = (n & 1) ? (b0 * s + b1 * c) : (b0 * c - b1 * s);
            outC = (n & 1) ? (c0 * s + c1 * c) : (c0 * c - c1 * s);
        } else {
            outB = sB[r][n] * scB[r] * Bnw[n] * Bbias[(h * RRANK + r) * NSTATE + n];
            outC = sC[r][n] * scC[r] * Cnw[n] * Cbias[(h * RRANK + r) * NSTATE + n];
        }
        size_t o = ((size_t)((b * RRANK + r) * NHEAD + h) * SEQ + l) * NSTATE + n;
        Bh[o] = outB;
        Ch[o] = outC;
    }
}

// ---------------- att: per (b,r,h) attention-shaped scan ----------------
// y[t,p] = sum_{j<=t} exp(P[t]-P[j]) * (u1[j] + [j<t]*u2[j]) * (C_t . B_j) * x[j,p]*mv[p]
__global__ __launch_bounds__(256) void att_kernel(const float* __restrict__ proj,
        const float* __restrict__ Bh, const float* __restrict__ Ch,
        const float* __restrict__ P, const float* __restrict__ DTv,
        const float* __restrict__ lamv, const float* __restrict__ mimo_x,
        float* __restrict__ Yr) {
    int brh = blockIdx.x;           // (b*RRANK+r)*NHEAD + h
    int h = brh % NHEAD;
    int r = (brh / NHEAD) % RRANK;
    int b = brh / (NHEAD * RRANK);
    int tid = threadIdx.x;
    __shared__ float Cs[64][65], Bs[64][65], Xs[64][65];
    __shared__ float Pl[SEQ], u1[SEQ], u2[SEQ], mvs[HDIM];
    int bh = b * NHEAD + h;
    for (int t = tid; t < SEQ; t += 256) {
        Pl[t] = P[bh * SEQ + t];
        float dt = DTv[bh * SEQ + t], lm = lamv[bh * SEQ + t];
        u1[t] = dt * lm;
        u2[t] = (t + 1 < SEQ) ? DTv[bh * SEQ + t + 1] * (1.f - lamv[bh * SEQ + t + 1]) : 0.f;
    }
    if (tid < HDIM) mvs[tid] = mimo_x[(h * RRANK + r) * HDIM + tid];

    const int tl = tid >> 2, pg = tid & 3, p0 = pg * 16;
    const size_t base = (size_t)brh * SEQ * NSTATE;
    for (int tt = 0; tt < 4; ++tt) {
        __syncthreads();   // prev compute done; also makes setup visible at tt=0
        for (int i = tid; i < 64 * 64; i += 256) {
            int rr_ = i >> 6, cc = i & 63;
            Cs[rr_][cc] = Ch[base + (size_t)(tt * 64 + rr_) * NSTATE + cc];
        }
        float acc[16];
        #pragma unroll
        for (int i = 0; i < 16; ++i) acc[i] = 0.f;
        const int t = tt * 64 + tl;
        float Pt = 0.f;
        for (int jt = 0; jt <= tt; ++jt) {
            __syncthreads();  // Cs ready / prev Bs,Xs consumers done
            for (int i = tid; i < 64 * 64; i += 256) {
                int rr_ = i >> 6, cc = i & 63;
                Bs[rr_][cc] = Bh[base + (size_t)(jt * 64 + rr_) * NSTATE + cc];
                Xs[rr_][cc] = proj[(size_t)(b * SEQ + jt * 64 + rr_) * DINP + COL_X + h * HDIM + cc]
                              * mvs[cc];
            }
            __syncthreads();
            Pt = Pl[t];
            const int jmax = (jt == tt) ? tl : 63;
            for (int j0 = 0; j0 <= jmax; ++j0) {
                int j = jt * 64 + j0;
                float g = 0.f;
                #pragma unroll 8
                for (int n = 0; n < 64; ++n) g += Cs[tl][n] * Bs[j0][n];
                float w = expf(Pt - Pl[j]) * (u1[j] + ((j < t) ? u2[j] : 0.f));
                float wg = w * g;
                #pragma unroll
                for (int pp = 0; pp < 16; ++pp) acc[pp] += wg * Xs[j0][p0 + pp];
            }
        }
        size_t yo = ((size_t)brh * SEQ + t) * HDIM + p0;
        #pragma unroll
        for (int pp = 0; pp < 16; ++pp) Yr[yo + pp] = acc[pp];
    }
}

// ---------------- combine: sum over r, +D*x, *silu(z) ----------------
__global__ void combine(const float* __restrict__ proj, const float* __restrict__ Yr,
                        const float* __restrict__ mimo_o, const float* __restrict__ Dp,
                        float* __restrict__ Yc) {
    int idx = blockIdx.x * 256 + threadIdx.x;  // over BATCH*SEQ*DIEXP
    if (idx >= BATCH * SEQ * DIEXP) return;
    int p = idx % HDIM;
    int h = (idx / HDIM) % NHEAD;
    int t = (idx / DIEXP) % SEQ;
    int b = idx / (DIEXP * SEQ);
    size_t y0 = ((size_t)((b * RRANK + 0) * NHEAD + h) * SEQ + t) * HDIM + p;
    size_t y1 = ((size_t)((b * RRANK + 1) * NHEAD + h) * SEQ + t) * HDIM + p;
    float yc = Yr[y0] * mimo_o[(h * RRANK + 0) * HDIM + p]
             + Yr[y1] * mimo_o[(h * RRANK + 1) * HDIM + p];
    const float* row = proj + (size_t)(b * SEQ + t) * DINP;
    float xv = row[COL_X + h * HDIM + p];
    float zv = row[COL_Z + h * HDIM + p];
    yc += Dp[h] * xv;
    Yc[idx] = yc * zv * sigmoidf_(zv);
}

// ---------------- launch ----------------
extern "C" void kernel_launch(void* const* d_in, const int* in_sizes, int n_in,
                              void* d_out, int out_size, void* d_ws, size_t ws_size,
                              hipStream_t stream) {
    const float* u        = (const float*)d_in[0];
    const float* in_w     = (const float*)d_in[1];
    const float* dt_bias  = (const float*)d_in[2];
    const float* B_bias   = (const float*)d_in[3];
    const float* C_bias   = (const float*)d_in[4];
    const float* B_norm_w = (const float*)d_in[5];
    const float* C_norm_w = (const float*)d_in[6];
    const float* mimo_x   = (const float*)d_in[7];
    const float* mimo_o   = (const float*)d_in[8];
    const float* Dvec     = (const float*)d_in[9];
    const float* out_w    = (const float*)d_in[10];
    float* out = (float*)d_out;

    float* ws = (float*)d_ws;
    float* proj  = ws;                       // 512*3416      = 1,748,992
    float* Bhp   = proj  + 1748992;          // 1,572,864
    float* Chp   = Bhp   + 1572864;          // 1,572,864
    float* theta = Chp   + 1572864;          // 196,608
    float* Pc    = theta + 196608;           // 12,288
    float* DTv   = Pc    + 12288;            // 12,288
    float* lamv  = DTv   + 12288;            // 12,288
    float* lav   = lamv  + 12288;            // 12,288
    float* Yr    = lav   + 12288;            // 1,572,864
    float* Yc    = Yr    + 1572864;          // 786,432   (total ~30 MB)

    const int M = BATCH * SEQ;  // 512

    // 1) proj = u @ in_proj_w^T      (512 x 3416, K=768)
    gemm_abt<<<dim3((DINP + 63) / 64, M / 64), 256, 0, stream>>>(u, in_w, proj, M, DINP, DMODL);
    // 2) per-(b,l,h) scalars
    prep1<<<(BATCH * SEQ * NHEAD + 255) / 256, 256, 0, stream>>>(proj, dt_bias, DTv, lamv, lav);
    // 3) cumulative log-decay
    prep2a<<<1, 64, 0, stream>>>(lav, Pc);
    // 4) theta cumsum
    prep2b<<<(BATCH * NHEAD * NANG + 255) / 256, 256, 0, stream>>>(proj, DTv, theta);
    // 5) RMS + bias + RoPE
    prep3<<<BATCH * SEQ, 256, 0, stream>>>(proj, B_bias, C_bias, B_norm_w, C_norm_w,
                                           theta, Bhp, Chp);
    // 6) attention-shaped scan
    att_kernel<<<BATCH * RRANK * NHEAD, 256, 0, stream>>>(proj, Bhp, Chp, Pc, DTv, lamv,
                                                          mimo_x, Yr);
    // 7) combine + gate
    combine<<<(BATCH * SEQ * DIEXP + 255) / 256, 256, 0, stream>>>(proj, Yr, mimo_o, Dvec, Yc);
    // 8) out = Yc @ out_proj_w^T    (512 x 768, K=1536)
    gemm_abt<<<dim3(DMODL / 64, M / 64), 256, 0, stream>>>(Yc, out_w, out, M, DMODL, DIEXP);
}

// Round 2
// 135.869 us; speedup vs baseline: 7.0434x; 7.0434x over previous
//
#include <hip/hip_runtime.h>
#include <hip/hip_bf16.h>
#include <math.h>

typedef __bf16 bf16x8 __attribute__((ext_vector_type(8)));
typedef float  f32x4  __attribute__((ext_vector_type(4)));

// ---------------- problem constants ----------------
#define BATCH 2
#define SEQ   256
#define DMODL 768
#define DIEXP 1536
#define NHEAD 24
#define HDIM  64
#define NSTATE 64
#define RRANK 2
#define NANG  16
#define HALFSPLIT 32
#define DINP  3416
#define DINP_PAD 3456     // padded to 27*128
#define AFLOOR 1e-4f
#define EPSV   1e-5f

#define COL_Z    0
#define COL_X    1536
#define COL_B    3072
#define COL_C    3200
#define COL_DT   3328
#define COL_A    3352
#define COL_TRAP 3376
#define COL_ANG  3400

__device__ __forceinline__ float softplusf(float x) {
    if (x > 20.f) return x;
    return log1pf(expf(x));
}
__device__ __forceinline__ float sigmoidf_(float x) {
    return 1.f / (1.f + expf(-x));
}
__device__ __forceinline__ ushort f2bf(float f) {
    uint u = __float_as_uint(f);
    uint r = (u + 0x7FFFu + ((u >> 16) & 1u)) >> 16;
    return (ushort)r;
}

// ---------------- convert inputs to bf16 (weights padded) ----------------
__global__ void to_bf16_all(const float* __restrict__ u, const float* __restrict__ win,
                            const float* __restrict__ wout,
                            ushort* __restrict__ u_bf, ushort* __restrict__ win_bf,
                            ushort* __restrict__ wout_bf) {
    const int NU  = 512 * 768;
    const int NWI = DINP_PAD * 768;
    const int NWO = 768 * 1536;
    int idx = blockIdx.x * 256 + threadIdx.x;
    if (idx < NU) {
        u_bf[idx] = f2bf(u[idx]);
    } else if (idx < NU + NWI) {
        int t = idx - NU;
        win_bf[t] = (t < DINP * 768) ? f2bf(win[t]) : (ushort)0;
    } else if (idx < NU + NWI + NWO) {
        int t = idx - NU - NWI;
        wout_bf[t] = f2bf(wout[t]);
    }
}

// ---------------- bf16 MFMA GEMM: C[M,N] = A[M,K] @ W[N,K]^T ----------------
// 128x128 tile, 4 waves (2x2), each wave 64x64 = 4x4 fragments of 16x16, K%32==0.
// Direct-global fragment loads (no LDS): all operand reads are contiguous 16B/lane.
__global__ __launch_bounds__(256) void gemm_bf16(const ushort* __restrict__ A,
        const ushort* __restrict__ W, float* __restrict__ C, int K, int Nstore) {
    const int bm = blockIdx.y * 128, bn = blockIdx.x * 128;
    const int wv = threadIdx.x >> 6, lane = threadIdx.x & 63;
    const int wr = (wv >> 1) * 64, wc = (wv & 1) * 64;
    const int r16 = lane & 15, kg = (lane >> 4) * 8;
    f32x4 acc[4][4];
    #pragma unroll
    for (int m = 0; m < 4; ++m)
        #pragma unroll
        for (int n = 0; n < 4; ++n) acc[m][n] = (f32x4){0.f, 0.f, 0.f, 0.f};
    const ushort* Ab = A + (size_t)(bm + wr + r16) * K + kg;
    const ushort* Wb = W + (size_t)(bn + wc + r16) * K + kg;
    for (int k0 = 0; k0 < K; k0 += 32) {
        bf16x8 af[4], bfr[4];
        #pragma unroll
        for (int m = 0; m < 4; ++m)
            af[m] = *(const bf16x8*)(Ab + (size_t)m * 16 * K + k0);
        #pragma unroll
        for (int n = 0; n < 4; ++n)
            bfr[n] = *(const bf16x8*)(Wb + (size_t)n * 16 * K + k0);
        #pragma unroll
        for (int m = 0; m < 4; ++m)
            #pragma unroll
            for (int n = 0; n < 4; ++n)
                acc[m][n] = __builtin_amdgcn_mfma_f32_16x16x32_bf16(af[m], bfr[n], acc[m][n], 0, 0, 0);
    }
    const int row0 = bm + wr + (lane >> 4) * 4;
    const int col0 = bn + wc + r16;
    #pragma unroll
    for (int n = 0; n < 4; ++n) {
        int col = col0 + n * 16;
        if (col >= Nstore) continue;
        #pragma unroll
        for (int m = 0; m < 4; ++m)
            #pragma unroll
            for (int r = 0; r < 4; ++r)
                C[(size_t)(row0 + m * 16 + r) * Nstore + col] = acc[m][n][r];
    }
}

// ---------------- scan: per (b,h) scalars + wave-parallel cumsums ----------------
// Replaces prep1/prep2a/prep2b (those were serial 256-step global chains).
__global__ __launch_bounds__(256) void scan_kernel(const float* __restrict__ proj,
        const float* __restrict__ dt_bias, float* __restrict__ DTv,
        float* __restrict__ lamv, float* __restrict__ Pc, float* __restrict__ theta) {
    const int bh = blockIdx.x;
    const int b = bh / NHEAD, h = bh % NHEAD;
    const int tid = threadIdx.x;
    __shared__ float mm[SEQ][18];   // 16 ang*DT channels + la ; stride 18 -> 2-way banks
    const int l = tid;
    const float* row = proj + (size_t)(b * SEQ + l) * DINP;
    float DT  = softplusf(row[COL_DT + h] + dt_bias[h]);
    float Asp = fmaxf(softplusf(row[COL_A + h]), AFLOOR);
    float la  = -Asp * DT;
    float lam = sigmoidf_(row[COL_TRAP + h]);
    DTv[bh * SEQ + l] = DT;
    lamv[bh * SEQ + l] = lam;
    #pragma unroll
    for (int i = 0; i < NANG; ++i) mm[l][i] = DT * row[COL_ANG + i];
    mm[l][16] = la;
    __syncthreads();
    const int wv = tid >> 6, lane = tid & 63;
    for (int ch = wv; ch < 17; ch += 4) {
        float carry = 0.f;
        for (int seg = 0; seg < 4; ++seg) {
            float v = mm[seg * 64 + lane][ch];
            #pragma unroll
            for (int off = 1; off < 64; off <<= 1) {
                float t = __shfl_up(v, off);
                if (lane >= off) v += t;
            }
            v += carry;
            carry = __shfl(v, 63);
            int ll = seg * 64 + lane;
            if (ch < 16)
                theta[((size_t)(b * SEQ + ll) * NHEAD + h) * NANG + ch] = v;
            else
                Pc[bh * SEQ + ll] = v;
        }
    }
}

// ---------------- prep3: RMS-norm + bias + RoPE -> bf16 Bh, Ch [(b,r,h),l,n] ----
__global__ __launch_bounds__(256) void prep3(const float* __restrict__ proj,
        const float* __restrict__ Bbias, const float* __restrict__ Cbias,
        const float* __restrict__ Bnw, const float* __restrict__ Cnw,
        const float* __restrict__ theta,
        ushort* __restrict__ Bh, ushort* __restrict__ Ch) {
    int bl = blockIdx.x;
    int b = bl / SEQ, l = bl % SEQ;
    int tid = threadIdx.x;
    __shared__ float sB[RRANK][NSTATE], sC[RRANK][NSTATE], scale[4];
    __shared__ float thl[NHEAD * NANG];
    const float* row = proj + (size_t)bl * DINP;
    if (tid < 128) {
        int r = tid / 64, n = tid % 64;
        sB[r][n] = row[COL_B + r * NSTATE + n];
    } else {
        int t2 = tid - 128;
        int r = t2 / 64, n = t2 % 64;
        sC[r][n] = row[COL_C + r * NSTATE + n];
    }
    for (int k = tid; k < NHEAD * NANG; k += 256)
        thl[k] = theta[(size_t)bl * NHEAD * NANG + k];
    __syncthreads();
    int g = tid / 64, lane = tid % 64;
    float v = (g < 2) ? sB[g][lane] : sC[g - 2][lane];
    float ss = v * v;
    #pragma unroll
    for (int off = 32; off; off >>= 1) ss += __shfl_xor(ss, off);
    if (lane == 0) scale[g] = rsqrtf(ss / NSTATE + EPSV);
    __syncthreads();
    float scB[2] = {scale[0], scale[1]};
    float scC[2] = {scale[2], scale[3]};
    for (int idx = tid; idx < RRANK * NHEAD * NSTATE; idx += 256) {
        int n = idx % NSTATE;
        int h = (idx / NSTATE) % NHEAD;
        int r = idx / (NSTATE * NHEAD);
        float outB, outC;
        if (n < HALFSPLIT) {
            int i = n >> 1;
            int n0 = i * 2, n1 = n0 + 1;
            float th = thl[h * NANG + i];
            float c = cosf(th), s = sinf(th);
            float b0 = sB[r][n0] * scB[r] * Bnw[n0] * Bbias[(h * RRANK + r) * NSTATE + n0];
            float b1 = sB[r][n1] * scB[r] * Bnw[n1] * Bbias[(h * RRANK + r) * NSTATE + n1];
            float c0 = sC[r][n0] * scC[r] * Cnw[n0] * Cbias[(h * RRANK + r) * NSTATE + n0];
            float c1 = sC[r][n1] * scC[r] * Cnw[n1] * Cbias[(h * RRANK + r) * NSTATE + n1];
            outB = (n & 1) ? (b0 * s + b1 * c) : (b0 * c - b1 * s);
            outC = (n & 1) ? (c0 * s + c1 * c) : (c0 * c - c1 * s);
        } else {
            outB = sB[r][n] * scB[r] * Bnw[n] * Bbias[(h * RRANK + r) * NSTATE + n];
            outC = sC[r][n] * scC[r] * Cnw[n] * Cbias[(h * RRANK + r) * NSTATE + n];
        }
        size_t o = ((size_t)((b * RRANK + r) * NHEAD + h) * SEQ + l) * NSTATE + n;
        Bh[o] = f2bf(outB);
        Ch[o] = f2bf(outC);
    }
}

// ---------------- xt: XT[bh][p][j] = bf16(x[b,j,h,p])  (mv factored out) -------
__global__ __launch_bounds__(256) void xt_prep(const float* __restrict__ proj,
                                               ushort* __restrict__ XT) {
    int bh = blockIdx.x;
    int b = bh / NHEAD, h = bh % NHEAD;
    __shared__ ushort tile[64][65];
    int tid = threadIdx.x;
    for (int jt = 0; jt < 4; ++jt) {
        __syncthreads();
        for (int i = tid; i < 4096; i += 256) {
            int j = i >> 6, p = i & 63;
            tile[j][p] = f2bf(proj[(size_t)(b * SEQ + jt * 64 + j) * DINP + COL_X + h * HDIM + p]);
        }
        __syncthreads();
        for (int i = tid; i < 4096; i += 256) {
            int p = i >> 6, j = i & 63;
            XT[((size_t)bh * HDIM + p) * SEQ + jt * 64 + j] = tile[j][p];
        }
    }
}

// ---------------- att: MFMA attention-shaped scan -------------------------------
// block = (brh, tt); 4 waves, wave w owns rows [tt*64+w*16, +16).
// Gram G = C_rows @ B_rows^T (bf16 MFMA), weight in fp32, repack to bf16 A-layout
// via per-wave LDS, then PV against XT (bf16 MFMA), fp32 out.
__global__ __launch_bounds__(256) void att_mfma(const ushort* __restrict__ Bh,
        const ushort* __restrict__ Ch, const ushort* __restrict__ XT,
        const float* __restrict__ Pc, const float* __restrict__ DTv,
        const float* __restrict__ lamv, float* __restrict__ Yr) {
    const int brh = blockIdx.x, tt = blockIdx.y;
    const int h = brh % NHEAD;
    const int b = brh / (NHEAD * RRANK);
    const int bh = b * NHEAD + h;
    const int tid = threadIdx.x, wv = tid >> 6, lane = tid & 63;
    __shared__ float Pl[SEQ], u1s[SEQ], u2s[SEQ];
    __shared__ ushort Pld[4][16][72];   // row stride 144B = 9*16B (aligned b128 reads)
    for (int t = tid; t < SEQ; t += 256) {
        Pl[t]  = Pc[bh * SEQ + t];
        u1s[t] = DTv[bh * SEQ + t] * lamv[bh * SEQ + t];
        u2s[t] = (t + 1 < SEQ) ? DTv[bh * SEQ + t + 1] * (1.f - lamv[bh * SEQ + t + 1]) : 0.f;
    }
    __syncthreads();
    const int r16 = lane & 15, kg = (lane >> 4) * 8;
    const int trow = tt * 64 + wv * 16;
    const ushort* cp = Ch + ((size_t)brh * SEQ + trow + r16) * NSTATE + kg;
    bf16x8 ca0 = *(const bf16x8*)cp;
    bf16x8 ca1 = *(const bf16x8*)(cp + 32);
    f32x4 yacc[4];
    #pragma unroll
    for (int pf = 0; pf < 4; ++pf) yacc[pf] = (f32x4){0.f, 0.f, 0.f, 0.f};
    const int tr0 = trow + (lane >> 4) * 4;
    float Pt[4];
    #pragma unroll
    for (int r = 0; r < 4; ++r) Pt[r] = Pl[tr0 + r];
    for (int jt = 0; jt <= tt; ++jt) {
        #pragma unroll
        for (int nf = 0; nf < 4; ++nf) {
            const ushort* bp = Bh + ((size_t)brh * SEQ + jt * 64 + nf * 16 + r16) * NSTATE + kg;
            bf16x8 b0 = *(const bf16x8*)bp;
            bf16x8 b1 = *(const bf16x8*)(bp + 32);
            f32x4 g = (f32x4){0.f, 0.f, 0.f, 0.f};
            g = __builtin_amdgcn_mfma_f32_16x16x32_bf16(ca0, b0, g, 0, 0, 0);
            g = __builtin_amdgcn_mfma_f32_16x16x32_bf16(ca1, b1, g, 0, 0, 0);
            const int j = jt * 64 + nf * 16 + r16;
            const float Pj = Pl[j], v1 = u1s[j], v2 = u2s[j];
            #pragma unroll
            for (int r = 0; r < 4; ++r) {
                const int t = tr0 + r;
                float wgt = 0.f;
                if (j <= t) wgt = expf(Pt[r] - Pj) * (v1 + ((j < t) ? v2 : 0.f));
                Pld[wv][(lane >> 4) * 4 + r][nf * 16 + r16] = f2bf(g[r] * wgt);
            }
        }
        bf16x8 pa0 = *(const bf16x8*)&Pld[wv][r16][kg];
        bf16x8 pa1 = *(const bf16x8*)&Pld[wv][r16][32 + kg];
        #pragma unroll
        for (int pf = 0; pf < 4; ++pf) {
            const ushort* xp = XT + ((size_t)bh * HDIM + pf * 16 + r16) * SEQ + jt * 64 + kg;
            bf16x8 x0 = *(const bf16x8*)xp;
            bf16x8 x1 = *(const bf16x8*)(xp + 32);
            yacc[pf] = __builtin_amdgcn_mfma_f32_16x16x32_bf16(pa0, x0, yacc[pf], 0, 0, 0);
            yacc[pf] = __builtin_amdgcn_mfma_f32_16x16x32_bf16(pa1, x1, yacc[pf], 0, 0, 0);
        }
    }
    #pragma unroll
    for (int pf = 0; pf < 4; ++pf)
        #pragma unroll
        for (int r = 0; r < 4; ++r)
            Yr[((size_t)brh * SEQ + tr0 + r) * HDIM + pf * 16 + r16] = yacc[pf][r];
}

// ---------------- combine: sum_r Yr*mv*mo + D*x, *silu(z), -> bf16 -------------
__global__ void combine(const float* __restrict__ proj, const float* __restrict__ Yr,
                        const float* __restrict__ mimo_x, const float* __restrict__ mimo_o,
                        const float* __restrict__ Dp, ushort* __restrict__ Yc) {
    int idx = blockIdx.x * 256 + threadIdx.x;
    if (idx >= BATCH * SEQ * DIEXP) return;
    int p = idx % HDIM;
    int h = (idx / HDIM) % NHEAD;
    int t = (idx / DIEXP) % SEQ;
    int b = idx / (DIEXP * SEQ);
    float mm0 = mimo_x[(h * RRANK + 0) * HDIM + p] * mimo_o[(h * RRANK + 0) * HDIM + p];
    float mm1 = mimo_x[(h * RRANK + 1) * HDIM + p] * mimo_o[(h * RRANK + 1) * HDIM + p];
    size_t y0 = ((size_t)((b * RRANK + 0) * NHEAD + h) * SEQ + t) * HDIM + p;
    size_t y1 = ((size_t)((b * RRANK + 1) * NHEAD + h) * SEQ + t) * HDIM + p;
    const float* row = proj + (size_t)(b * SEQ + t) * DINP;
    float xv = row[COL_X + h * HDIM + p];
    float zv = row[COL_Z + h * HDIM + p];
    float y = Yr[y0] * mm0 + Yr[y1] * mm1 + Dp[h] * xv;
    y *= zv * sigmoidf_(zv);
    Yc[idx] = f2bf(y);
}

// ---------------- launch ----------------
extern "C" void kernel_launch(void* const* d_in, const int* in_sizes, int n_in,
                              void* d_out, int out_size, void* d_ws, size_t ws_size,
                              hipStream_t stream) {
    const float* u        = (const float*)d_in[0];
    const float* in_w     = (const float*)d_in[1];
    const float* dt_bias  = (const float*)d_in[2];
    const float* B_bias   = (const float*)d_in[3];
    const float* C_bias   = (const float*)d_in[4];
    const float* B_norm_w = (const float*)d_in[5];
    const float* C_norm_w = (const float*)d_in[6];
    const float* mimo_x   = (const float*)d_in[7];
    const float* mimo_o   = (const float*)d_in[8];
    const float* Dvec     = (const float*)d_in[9];
    const float* out_w    = (const float*)d_in[10];
    float* out = (float*)d_out;

    float* ws = (float*)d_ws;
    float*  proj    = ws;                          // 1,748,992 f
    ushort* u_bf    = (ushort*)(proj + 1748992);   // 393,216 us   (196,608 f)
    ushort* win_bf  = (ushort*)(proj + 1945600);   // 2,654,208 us (1,327,104 f)
    ushort* wout_bf = (ushort*)(proj + 3272704);   // 1,179,648 us (589,824 f)
    ushort* Bh_bf   = (ushort*)(proj + 3862528);   // 1,572,864 us (786,432 f)
    ushort* Ch_bf   = (ushort*)(proj + 4648960);   // 1,572,864 us (786,432 f)
    ushort* XT_bf   = (ushort*)(proj + 5435392);   // 786,432 us   (393,216 f)
    float*  theta   = proj + 5828608;              // 196,608 f
    float*  Pc      = proj + 6025216;              // 12,288 f
    float*  DTv     = proj + 6037504;              // 12,288 f
    float*  lamv    = proj + 6049792;              // 12,288 f
    float*  Yr      = proj + 6062080;              // 1,572,864 f
    ushort* Yc_bf   = (ushort*)(proj + 7634944);   // 786,432 us   (393,216 f) -> total ~32.1 MB

    // 1) fp32 -> bf16 conversions (u, in_w padded to 3456 rows, out_w)
    to_bf16_all<<<16512, 256, 0, stream>>>(u, in_w, out_w, u_bf, win_bf, wout_bf);
    // 2) proj = u @ in_proj_w^T   (512 x 3416, K=768), bf16 MFMA
    gemm_bf16<<<dim3(DINP_PAD / 128, 4), 256, 0, stream>>>(u_bf, win_bf, proj, DMODL, DINP);
    // 3) scalars + wave-parallel cumsums (P, theta)
    scan_kernel<<<BATCH * NHEAD, 256, 0, stream>>>(proj, dt_bias, DTv, lamv, Pc, theta);
    // 4) RMS + bias + RoPE -> bf16
    prep3<<<BATCH * SEQ, 256, 0, stream>>>(proj, B_bias, C_bias, B_norm_w, C_norm_w,
                                           theta, Bh_bf, Ch_bf);
    // 5) x transpose -> bf16 XT
    xt_prep<<<BATCH * NHEAD, 256, 0, stream>>>(proj, XT_bf);
    // 6) MFMA attention-shaped scan
    att_mfma<<<dim3(BATCH * RRANK * NHEAD, 4), 256, 0, stream>>>(Bh_bf, Ch_bf, XT_bf,
                                                                 Pc, DTv, lamv, Yr);
    // 7) combine + gate -> bf16
    combine<<<(BATCH * SEQ * DIEXP + 255) / 256, 256, 0, stream>>>(proj, Yr, mimo_x,
                                                                   mimo_o, Dvec, Yc_bf);
    // 8) out = Yc @ out_proj_w^T  (512 x 768, K=1536), bf16 MFMA
    gemm_bf16<<<dim3(DMODL / 128, 4), 256, 0, stream>>>(Yc_bf, wout_bf, out, DIEXP, DMODL);
}

// Round 3
// 98.705 us; speedup vs baseline: 9.6953x; 1.3765x over previous
//
#include <hip/hip_runtime.h>
#include <hip/hip_bf16.h>
#include <math.h>

typedef __bf16 bf16x8 __attribute__((ext_vector_type(8)));
typedef float  f32x4  __attribute__((ext_vector_type(4)));

// ---------------- problem constants ----------------
#define BATCH 2
#define SEQ   256
#define DMODL 768
#define DIEXP 1536
#define NHEAD 24
#define HDIM  64
#define NSTATE 64
#define RRANK 2
#define NANG  16
#define HALFSPLIT 32
#define DINP  3416
#define DINP_PAD 3456     // 27*128
#define AFLOOR 1e-4f
#define EPSV   1e-5f

#define COL_Z    0
#define COL_X    1536
#define COL_B    3072
#define COL_C    3200
#define COL_DT   3328
#define COL_A    3352
#define COL_TRAP 3376
#define COL_ANG  3400

__device__ __forceinline__ float softplusf(float x) {
    if (x > 20.f) return x;
    return log1pf(expf(x));
}
__device__ __forceinline__ float sigmoidf_(float x) {
    return 1.f / (1.f + expf(-x));
}
__device__ __forceinline__ ushort f2bf(float f) {
    uint u = __float_as_uint(f);
    uint r = (u + 0x7FFFu + ((u >> 16) & 1u)) >> 16;
    return (ushort)r;
}

// ---------------- fused fp32->bf16 MFMA GEMM: C[M,N] = A[M,K] @ W[N,K]^T -------
// BM=64, BN in {64,128}, BK=64, 256 threads = 4 waves (2x2), wave = 32 x BN/2.
// fp32 global operands converted to bf16 during LDS staging (no separate pass).
// LDS XOR-swizzle (byte ^= (row&7)<<4) keeps ds_read_b128 at <=2-way conflict.
template<int BN>
__global__ __launch_bounds__(256) void gemm_f32mfma(const float* __restrict__ A,
        const float* __restrict__ W, float* __restrict__ C,
        int Nw, int K, int Nstore) {
    constexpr int NF = BN / 32;          // n-frags per wave
    constexpr int WPASS = BN / 16;       // W staging passes
    const int bm = blockIdx.y * 64, bn = blockIdx.x * BN;
    const int tid = threadIdx.x;
    const int wv = tid >> 6, lane = tid & 63;
    const int wr = (wv >> 1) * 32, wc = (wv & 1) * (BN / 2);
    __shared__ ushort As[2][64 * 64];
    __shared__ ushort Bs[2][BN * 64];
    const int srow = tid >> 4, sc4 = tid & 15;
    const int NT = K >> 6;
    float4 ra[4], rw[WPASS];

    auto load_tile = [&](int t) {
        const int k0 = t * 64;
        #pragma unroll
        for (int p = 0; p < 4; ++p) {
            int r = p * 16 + srow;
            ra[p] = *(const float4*)(A + (size_t)(bm + r) * K + k0 + sc4 * 4);
        }
        #pragma unroll
        for (int p = 0; p < WPASS; ++p) {
            int r = p * 16 + srow;
            rw[p] = (bn + r < Nw)
                  ? *(const float4*)(W + (size_t)(bn + r) * K + k0 + sc4 * 4)
                  : (float4){0.f, 0.f, 0.f, 0.f};
        }
    };
    auto write_tile = [&](int buf) {
        #pragma unroll
        for (int p = 0; p < 4; ++p) {
            int r = p * 16 + srow;
            int byt = (sc4 * 8) ^ ((r & 7) << 4);
            ushort4 h;
            h.x = f2bf(ra[p].x); h.y = f2bf(ra[p].y);
            h.z = f2bf(ra[p].z); h.w = f2bf(ra[p].w);
            *(ushort4*)(&As[buf][r * 64 + (byt >> 1)]) = h;
        }
        #pragma unroll
        for (int p = 0; p < WPASS; ++p) {
            int r = p * 16 + srow;
            int byt = (sc4 * 8) ^ ((r & 7) << 4);
            ushort4 h;
            h.x = f2bf(rw[p].x); h.y = f2bf(rw[p].y);
            h.z = f2bf(rw[p].z); h.w = f2bf(rw[p].w);
            *(ushort4*)(&Bs[buf][r * 64 + (byt >> 1)]) = h;
        }
    };

    f32x4 acc[2][NF];
    #pragma unroll
    for (int m = 0; m < 2; ++m)
        #pragma unroll
        for (int n = 0; n < NF; ++n) acc[m][n] = (f32x4){0.f, 0.f, 0.f, 0.f};
    const int fr = lane & 15, fk = (lane >> 4) * 16;  // frag row/col, k-byte base

    auto compute = [&](int buf) {
        #pragma unroll
        for (int kk = 0; kk < 2; ++kk) {
            bf16x8 af[2], bff[NF];
            #pragma unroll
            for (int m = 0; m < 2; ++m) {
                int r = wr + m * 16 + fr;
                int byt = (kk * 64 + fk) ^ ((r & 7) << 4);
                af[m] = *(const bf16x8*)(&As[buf][r * 64 + (byt >> 1)]);
            }
            #pragma unroll
            for (int n = 0; n < NF; ++n) {
                int r = wc + n * 16 + fr;
                int byt = (kk * 64 + fk) ^ ((r & 7) << 4);
                bff[n] = *(const bf16x8*)(&Bs[buf][r * 64 + (byt >> 1)]);
            }
            #pragma unroll
            for (int m = 0; m < 2; ++m)
                #pragma unroll
                for (int n = 0; n < NF; ++n)
                    acc[m][n] = __builtin_amdgcn_mfma_f32_16x16x32_bf16(af[m], bff[n], acc[m][n], 0, 0, 0);
        }
    };

    load_tile(0);
    write_tile(0);
    __syncthreads();
    for (int t = 0; t < NT; ++t) {
        if (t + 1 < NT) load_tile(t + 1);     // issue next-tile global loads
        compute(t & 1);                        // ds_read + MFMA on current
        if (t + 1 < NT) write_tile((t + 1) & 1);  // cvt + ds_write (other buffer)
        __syncthreads();
    }

    const int r0 = bm + wr + (lane >> 4) * 4;
    #pragma unroll
    for (int n = 0; n < NF; ++n) {
        int col = bn + wc + n * 16 + fr;
        if (col >= Nstore) continue;
        #pragma unroll
        for (int m = 0; m < 2; ++m)
            #pragma unroll
            for (int r = 0; r < 4; ++r)
                C[(size_t)(r0 + m * 16 + r) * Nstore + col] = acc[m][n][r];
    }
}

// ---------------- scan: per (b,h) scalars + wave-parallel cumsums ----------------
__global__ __launch_bounds__(256) void scan_kernel(const float* __restrict__ proj,
        const float* __restrict__ dt_bias, float* __restrict__ DTv,
        float* __restrict__ lamv, float* __restrict__ Pc, float* __restrict__ theta) {
    const int bh = blockIdx.x;
    const int b = bh / NHEAD, h = bh % NHEAD;
    const int tid = threadIdx.x;
    __shared__ float mm[SEQ][18];
    const int l = tid;
    const float* row = proj + (size_t)(b * SEQ + l) * DINP;
    float DT  = softplusf(row[COL_DT + h] + dt_bias[h]);
    float Asp = fmaxf(softplusf(row[COL_A + h]), AFLOOR);
    float la  = -Asp * DT;
    float lam = sigmoidf_(row[COL_TRAP + h]);
    DTv[bh * SEQ + l] = DT;
    lamv[bh * SEQ + l] = lam;
    #pragma unroll
    for (int i = 0; i < NANG; ++i) mm[l][i] = DT * row[COL_ANG + i];
    mm[l][16] = la;
    __syncthreads();
    const int wv = tid >> 6, lane = tid & 63;
    for (int ch = wv; ch < 17; ch += 4) {
        float carry = 0.f;
        for (int seg = 0; seg < 4; ++seg) {
            float v = mm[seg * 64 + lane][ch];
            #pragma unroll
            for (int off = 1; off < 64; off <<= 1) {
                float t = __shfl_up(v, off);
                if (lane >= off) v += t;
            }
            v += carry;
            carry = __shfl(v, 63);
            int ll = seg * 64 + lane;
            if (ch < 16)
                theta[((size_t)(b * SEQ + ll) * NHEAD + h) * NANG + ch] = v;
            else
                Pc[bh * SEQ + ll] = v;
        }
    }
}

// ---------------- prep3: RMS-norm + bias + RoPE -> bf16 Bh, Ch [(b,r,h),l,n] ----
__global__ __launch_bounds__(256) void prep3(const float* __restrict__ proj,
        const float* __restrict__ Bbias, const float* __restrict__ Cbias,
        const float* __restrict__ Bnw, const float* __restrict__ Cnw,
        const float* __restrict__ theta,
        ushort* __restrict__ Bh, ushort* __restrict__ Ch) {
    int bl = blockIdx.x;
    int b = bl / SEQ, l = bl % SEQ;
    int tid = threadIdx.x;
    __shared__ float sB[RRANK][NSTATE], sC[RRANK][NSTATE], scale[4];
    __shared__ float thl[NHEAD * NANG];
    const float* row = proj + (size_t)bl * DINP;
    if (tid < 128) {
        int r = tid / 64, n = tid % 64;
        sB[r][n] = row[COL_B + r * NSTATE + n];
    } else {
        int t2 = tid - 128;
        int r = t2 / 64, n = t2 % 64;
        sC[r][n] = row[COL_C + r * NSTATE + n];
    }
    for (int k = tid; k < NHEAD * NANG; k += 256)
        thl[k] = theta[(size_t)bl * NHEAD * NANG + k];
    __syncthreads();
    int g = tid / 64, lane = tid % 64;
    float v = (g < 2) ? sB[g][lane] : sC[g - 2][lane];
    float ss = v * v;
    #pragma unroll
    for (int off = 32; off; off >>= 1) ss += __shfl_xor(ss, off);
    if (lane == 0) scale[g] = rsqrtf(ss / NSTATE + EPSV);
    __syncthreads();
    float scB[2] = {scale[0], scale[1]};
    float scC[2] = {scale[2], scale[3]};
    for (int idx = tid; idx < RRANK * NHEAD * NSTATE; idx += 256) {
        int n = idx % NSTATE;
        int h = (idx / NSTATE) % NHEAD;
        int r = idx / (NSTATE * NHEAD);
        float outB, outC;
        if (n < HALFSPLIT) {
            int i = n >> 1;
            int n0 = i * 2, n1 = n0 + 1;
            float th = thl[h * NANG + i];
            float c = cosf(th), s = sinf(th);
            float b0 = sB[r][n0] * scB[r] * Bnw[n0] * Bbias[(h * RRANK + r) * NSTATE + n0];
            float b1 = sB[r][n1] * scB[r] * Bnw[n1] * Bbias[(h * RRANK + r) * NSTATE + n1];
            float c0 = sC[r][n0] * scC[r] * Cnw[n0] * Cbias[(h * RRANK + r) * NSTATE + n0];
            float c1 = sC[r][n1] * scC[r] * Cnw[n1] * Cbias[(h * RRANK + r) * NSTATE + n1];
            outB = (n & 1) ? (b0 * s + b1 * c) : (b0 * c - b1 * s);
            outC = (n & 1) ? (c0 * s + c1 * c) : (c0 * c - c1 * s);
        } else {
            outB = sB[r][n] * scB[r] * Bnw[n] * Bbias[(h * RRANK + r) * NSTATE + n];
            outC = sC[r][n] * scC[r] * Cnw[n] * Cbias[(h * RRANK + r) * NSTATE + n];
        }
        size_t o = ((size_t)((b * RRANK + r) * NHEAD + h) * SEQ + l) * NSTATE + n;
        Bh[o] = f2bf(outB);
        Ch[o] = f2bf(outC);
    }
}

// ---------------- xt: XT[bh][p][j] = bf16(x[b,j,h,p]) ----------------
__global__ __launch_bounds__(256) void xt_prep(const float* __restrict__ proj,
                                               ushort* __restrict__ XT) {
    int bh = blockIdx.x;
    int b = bh / NHEAD, h = bh % NHEAD;
    __shared__ ushort tile[64][65];
    int tid = threadIdx.x;
    for (int jt = 0; jt < 4; ++jt) {
        __syncthreads();
        for (int i = tid; i < 4096; i += 256) {
            int j = i >> 6, p = i & 63;
            tile[j][p] = f2bf(proj[(size_t)(b * SEQ + jt * 64 + j) * DINP + COL_X + h * HDIM + p]);
        }
        __syncthreads();
        for (int i = tid; i < 4096; i += 256) {
            int p = i >> 6, j = i & 63;
            XT[((size_t)bh * HDIM + p) * SEQ + jt * 64 + j] = tile[j][p];
        }
    }
}

// ---------------- att: MFMA attention-shaped scan -------------------------------
__global__ __launch_bounds__(256) void att_mfma(const ushort* __restrict__ Bh,
        const ushort* __restrict__ Ch, const ushort* __restrict__ XT,
        const float* __restrict__ Pc, const float* __restrict__ DTv,
        const float* __restrict__ lamv, float* __restrict__ Yr) {
    const int brh = blockIdx.x, tt = blockIdx.y;
    const int h = brh % NHEAD;
    const int b = brh / (NHEAD * RRANK);
    const int bh = b * NHEAD + h;
    const int tid = threadIdx.x, wv = tid >> 6, lane = tid & 63;
    __shared__ float Pl[SEQ], u1s[SEQ], u2s[SEQ];
    __shared__ ushort Pld[4][16][72];
    for (int t = tid; t < SEQ; t += 256) {
        Pl[t]  = Pc[bh * SEQ + t];
        u1s[t] = DTv[bh * SEQ + t] * lamv[bh * SEQ + t];
        u2s[t] = (t + 1 < SEQ) ? DTv[bh * SEQ + t + 1] * (1.f - lamv[bh * SEQ + t + 1]) : 0.f;
    }
    __syncthreads();
    const int r16 = lane & 15, kg = (lane >> 4) * 8;
    const int trow = tt * 64 + wv * 16;
    const ushort* cp = Ch + ((size_t)brh * SEQ + trow + r16) * NSTATE + kg;
    bf16x8 ca0 = *(const bf16x8*)cp;
    bf16x8 ca1 = *(const bf16x8*)(cp + 32);
    f32x4 yacc[4];
    #pragma unroll
    for (int pf = 0; pf < 4; ++pf) yacc[pf] = (f32x4){0.f, 0.f, 0.f, 0.f};
    const int tr0 = trow + (lane >> 4) * 4;
    float Pt[4];
    #pragma unroll
    for (int r = 0; r < 4; ++r) Pt[r] = Pl[tr0 + r];
    for (int jt = 0; jt <= tt; ++jt) {
        #pragma unroll
        for (int nf = 0; nf < 4; ++nf) {
            const ushort* bp = Bh + ((size_t)brh * SEQ + jt * 64 + nf * 16 + r16) * NSTATE + kg;
            bf16x8 b0 = *(const bf16x8*)bp;
            bf16x8 b1 = *(const bf16x8*)(bp + 32);
            f32x4 g = (f32x4){0.f, 0.f, 0.f, 0.f};
            g = __builtin_amdgcn_mfma_f32_16x16x32_bf16(ca0, b0, g, 0, 0, 0);
            g = __builtin_amdgcn_mfma_f32_16x16x32_bf16(ca1, b1, g, 0, 0, 0);
            const int j = jt * 64 + nf * 16 + r16;
            const float Pj = Pl[j], v1 = u1s[j], v2 = u2s[j];
            #pragma unroll
            for (int r = 0; r < 4; ++r) {
                const int t = tr0 + r;
                float wgt = 0.f;
                if (j <= t) wgt = expf(Pt[r] - Pj) * (v1 + ((j < t) ? v2 : 0.f));
                Pld[wv][(lane >> 4) * 4 + r][nf * 16 + r16] = f2bf(g[r] * wgt);
            }
        }
        bf16x8 pa0 = *(const bf16x8*)&Pld[wv][r16][kg];
        bf16x8 pa1 = *(const bf16x8*)&Pld[wv][r16][32 + kg];
        #pragma unroll
        for (int pf = 0; pf < 4; ++pf) {
            const ushort* xp = XT + ((size_t)bh * HDIM + pf * 16 + r16) * SEQ + jt * 64 + kg;
            bf16x8 x0 = *(const bf16x8*)xp;
            bf16x8 x1 = *(const bf16x8*)(xp + 32);
            yacc[pf] = __builtin_amdgcn_mfma_f32_16x16x32_bf16(pa0, x0, yacc[pf], 0, 0, 0);
            yacc[pf] = __builtin_amdgcn_mfma_f32_16x16x32_bf16(pa1, x1, yacc[pf], 0, 0, 0);
        }
    }
    #pragma unroll
    for (int pf = 0; pf < 4; ++pf)
        #pragma unroll
        for (int r = 0; r < 4; ++r)
            Yr[((size_t)brh * SEQ + tr0 + r) * HDIM + pf * 16 + r16] = yacc[pf][r];
}

// ---------------- combine: sum_r Yr*mv*mo + D*x, *silu(z) -> fp32 Yc -----------
__global__ void combine(const float* __restrict__ proj, const float* __restrict__ Yr,
                        const float* __restrict__ mimo_x, const float* __restrict__ mimo_o,
                        const float* __restrict__ Dp, float* __restrict__ Yc) {
    int idx = blockIdx.x * 256 + threadIdx.x;
    if (idx >= BATCH * SEQ * DIEXP) return;
    int p = idx % HDIM;
    int h = (idx / HDIM) % NHEAD;
    int t = (idx / DIEXP) % SEQ;
    int b = idx / (DIEXP * SEQ);
    float mm0 = mimo_x[(h * RRANK + 0) * HDIM + p] * mimo_o[(h * RRANK + 0) * HDIM + p];
    float mm1 = mimo_x[(h * RRANK + 1) * HDIM + p] * mimo_o[(h * RRANK + 1) * HDIM + p];
    size_t y0 = ((size_t)((b * RRANK + 0) * NHEAD + h) * SEQ + t) * HDIM + p;
    size_t y1 = ((size_t)((b * RRANK + 1) * NHEAD + h) * SEQ + t) * HDIM + p;
    const float* row = proj + (size_t)(b * SEQ + t) * DINP;
    float xv = row[COL_X + h * HDIM + p];
    float zv = row[COL_Z + h * HDIM + p];
    float y = Yr[y0] * mm0 + Yr[y1] * mm1 + Dp[h] * xv;
    Yc[idx] = y * zv * sigmoidf_(zv);
}

// ---------------- launch ----------------
extern "C" void kernel_launch(void* const* d_in, const int* in_sizes, int n_in,
                              void* d_out, int out_size, void* d_ws, size_t ws_size,
                              hipStream_t stream) {
    const float* u        = (const float*)d_in[0];
    const float* in_w     = (const float*)d_in[1];
    const float* dt_bias  = (const float*)d_in[2];
    const float* B_bias   = (const float*)d_in[3];
    const float* C_bias   = (const float*)d_in[4];
    const float* B_norm_w = (const float*)d_in[5];
    const float* C_norm_w = (const float*)d_in[6];
    const float* mimo_x   = (const float*)d_in[7];
    const float* mimo_o   = (const float*)d_in[8];
    const float* Dvec     = (const float*)d_in[9];
    const float* out_w    = (const float*)d_in[10];
    float* out = (float*)d_out;

    float* ws = (float*)d_ws;
    float*  proj  = ws;                           // 1,748,992 f
    ushort* Bh_bf = (ushort*)(proj + 1748992);    // 786,432 f
    ushort* Ch_bf = (ushort*)(proj + 2535424);    // 786,432 f
    ushort* XT_bf = (ushort*)(proj + 3321856);    // 393,216 f
    float*  theta = proj + 3715072;               // 196,608 f
    float*  Pc    = proj + 3911680;               // 12,288 f
    float*  DTv   = proj + 3923968;               // 12,288 f
    float*  lamv  = proj + 3936256;               // 12,288 f
    float*  Yr    = proj + 3948544;               // 1,572,864 f
    float*  Yc    = proj + 5521408;               // 786,432 f   -> total ~25.2 MB

    // 1) proj = u @ in_proj_w^T  (512 x 3416, K=768), fused fp32->bf16 staging
    gemm_f32mfma<128><<<dim3(DINP_PAD / 128, 8), 256, 0, stream>>>(u, in_w, proj,
                                                                   DINP, DMODL, DINP);
    // 2) scalars + wave-parallel cumsums (P, theta)
    scan_kernel<<<BATCH * NHEAD, 256, 0, stream>>>(proj, dt_bias, DTv, lamv, Pc, theta);
    // 3) RMS + bias + RoPE -> bf16
    prep3<<<BATCH * SEQ, 256, 0, stream>>>(proj, B_bias, C_bias, B_norm_w, C_norm_w,
                                           theta, Bh_bf, Ch_bf);
    // 4) x transpose -> bf16 XT
    xt_prep<<<BATCH * NHEAD, 256, 0, stream>>>(proj, XT_bf);
    // 5) MFMA attention-shaped scan
    att_mfma<<<dim3(BATCH * RRANK * NHEAD, 4), 256, 0, stream>>>(Bh_bf, Ch_bf, XT_bf,
                                                                 Pc, DTv, lamv, Yr);
    // 6) combine + gate -> fp32 Yc
    combine<<<(BATCH * SEQ * DIEXP + 255) / 256, 256, 0, stream>>>(proj, Yr, mimo_x,
                                                                   mimo_o, Dvec, Yc);
    // 7) out = Yc @ out_proj_w^T  (512 x 768, K=1536), fused fp32->bf16 staging
    gemm_f32mfma<64><<<dim3(DMODL / 64, 8), 256, 0, stream>>>(Yc, out_w, out,
                                                              DMODL, DIEXP, DMODL);
}